// Round 11
// baseline (898.572 us; speedup 1.0000x reference)
//
#include <hip/hip_runtime.h>
#include <hip/hip_bf16.h>

// Problem dims (fixed by reference)
#define BATCH 16384
#define TT    64
#define INF   48
#define FF    32
#define TFD   2048   // T*F   (GEMM1 K)
#define THD   8192   // T*H   (GEMM1 N)

typedef __attribute__((ext_vector_type(8))) short bf16x8;
typedef __attribute__((ext_vector_type(4))) short bf16x4;
typedef __attribute__((ext_vector_type(4))) short short4v;
typedef __attribute__((ext_vector_type(4))) float f32x4;

#define SCHED __builtin_amdgcn_sched_barrier(0)
#define VMW(n) asm volatile("s_waitcnt vmcnt(" #n ")" ::: "memory")

__device__ inline void gload_lds16(const void* g, void* l) {
  __builtin_amdgcn_global_load_lds((const __attribute__((address_space(1))) void*)g,
                                   (__attribute__((address_space(3))) void*)l, 16, 0, 0);
}

__device__ inline f32x4 mfma16x16x16_bf16(bf16x4 a, bf16x4 b, f32x4 c) {
#if __has_builtin(__builtin_amdgcn_mfma_f32_16x16x16bf16_1k)
  return __builtin_amdgcn_mfma_f32_16x16x16bf16_1k(a, b, c, 0, 0, 0);
#else
  asm("v_mfma_f32_16x16x16_bf16 %0, %1, %2, %0" : "+v"(c) : "v"(a), "v"(b));
  return c;
#endif
}

__device__ inline short f32_to_bf16_bits(float x) {
  __hip_bfloat16 h = __float2bfloat16(x);
  return *reinterpret_cast<short*>(&h);
}

// ---------------- prep kernels ----------------

// xsf: fragment-linear X. Slot (g64, t, bi, lane):
//   element j: bf16( x[g64*64 + bi*16 + (lane&15)][t][sidx[(lane>>4)*8 + j]] )
__global__ void gather_cast_frag(const float* __restrict__ x, const int* __restrict__ sidx,
                                 __hip_bfloat16* __restrict__ xsf) {
  __shared__ int sx[FF];
  if (threadIdx.x < FF) sx[threadIdx.x] = sidx[threadIdx.x];
  __syncthreads();
  const int b64 = blockIdx.x >> 2;          // 0..255
  const int tq  = blockIdx.x & 3;           // t-quarter
  for (int it = 0; it < 16; ++it) {
    const int slot = (tq * 16 + it) * 256 + threadIdx.x;   // ((t*4+bi)*64+l)
    const int t  = slot >> 8;
    const int bi = (slot >> 6) & 3;
    const int l  = slot & 63;
    const int lo = l & 15, hi = l >> 4;
    const int row = b64 * 64 + bi * 16 + lo;
    const float* rp = x + ((size_t)row * TT + t) * INF;
    bf16x8 v;
    #pragma unroll
    for (int j = 0; j < 8; ++j) v[j] = f32_to_bf16_bits(rp[sx[hi * 8 + j]]);
    *(bf16x8*)(xsf + ((size_t)b64 * 16384 + slot) * 8) = v;
  }
}

// W1t[n][k] = bf16(W1[k][n]);  W1: [TFD][THD] row-major. ushort4 stores.
__global__ void transpose_w1(const float* __restrict__ W1, __hip_bfloat16* __restrict__ W1t) {
  __shared__ float tile[64][65];
  const int k0 = blockIdx.x * 64;
  const int n0 = blockIdx.y * 64;
  const int tx = threadIdx.x & 63, ty = threadIdx.x >> 6;
  for (int r = ty; r < 64; r += 4)
    tile[r][tx] = W1[(size_t)(k0 + r) * THD + n0 + tx];
  __syncthreads();
  const int rn = threadIdx.x >> 4;          // 0..15
  const int kq = (threadIdx.x & 15) * 4;    // k-quad
  for (int rr = rn; rr < 64; rr += 16) {
    short4v v;
    #pragma unroll
    for (int i = 0; i < 4; ++i) v[i] = f32_to_bf16_bits(tile[kq + i][rr]);
    *(short4v*)(W1t + (size_t)(n0 + rr) * TFD + k0 + kq) = v;
  }
}

// w2t[f][n] = bf16( sum_t W2[n][t*32+f]*weight[t][f] );  beff[f] = bias[f] + sum_t b2[t*32+f]*weight[t][f]
__global__ void make_w2eff(const float* __restrict__ W2, const float* __restrict__ b2,
                           const float* __restrict__ weight, const float* __restrict__ bias,
                           __hip_bfloat16* __restrict__ w2t, float* __restrict__ beff) {
  const int n = blockIdx.x * 8 + (threadIdx.x >> 5);
  const int f = threadIdx.x & 31;
  const float* wr = W2 + (size_t)n * TFD;
  float s = 0.f;
  #pragma unroll 8
  for (int t = 0; t < TT; ++t) s += wr[t * FF + f] * weight[t * FF + f];
  w2t[(size_t)f * THD + n] = __float2bfloat16(s);
  if (blockIdx.x == 0 && threadIdx.x < FF) {
    float sb = bias[f];
    for (int t = 0; t < TT; ++t) sb += b2[t * FF + f] * weight[t * FF + f];
    beff[f] = sb;
  }
}

// ---------------- main fused GEMM ----------------
// r11 = r9 geometry (256 batch x 256 n, 8 waves = 2 mq x 4 bq, 512 thr,
// 1 block/CU) with a K64 iteration, 4 x 32KB LDS buffers (stage-2-ahead),
// and FORCED ANTI-PHASE: SIMD-mates are (wid, wid+4) = opposite mq; mq=0
// computes K-half A then B, mq=1 computes B then A, so one mate's MFMA
// covers the other's LDS-read/stage section by construction (r9 measured
// the two phases serialized: 2490cyc/iter = 1242 MFMA + ~1250 fetch).
// Barrier every 2 K64-iters (K128 window, 2x sparser than r9).
// Safety: drift<2 => writes (t_f+2)&3 vs reads t_s&3 distance {1,2,3} != 0
// mod 4; publish: S(t+2) drains at same-iter W2 (FIFO: issued before both
// refills), barriers at even-t ends lie between drain and first read.
// vmcnt ledger (per wave; S=4, refill=4 loads): steady E(t)={Rfirst(t-1),
// Rsecond(t-1)}; W0 vmcnt(8) drains first-consumed refill; W1 vmcnt(8)
// drains second; W2 vmcnt(8) drains S(t+2). Prologue {S0,S1,Rf,Rs}:
// vmcnt(12) drains S0. Tail: t=30 -> 4/4 (no W2), t=31 -> 4/0.

__device__ inline void stage_w(char* buf, const __hip_bfloat16* __restrict__ w1t,
                               int n0, int k0, int wid, int l) {
  const int sub = l >> 3;
  const int c   = (l & 7) ^ sub;             // inverse chunk swizzle
  const int h   = c >> 2, kc = c & 3;
  const int r0  = wid * 8 + sub;             // lds row (128B rows, 2 logical rows each)
  const __hip_bfloat16* gw0 = w1t + (size_t)(n0 + 2 * r0 + h) * TFD + k0 + kc * 8;
  const __hip_bfloat16* gw1 = w1t + (size_t)(n0 + 128 + 2 * r0 + h) * TFD + k0 + kc * 8;
  char* lx = buf + wid * 1024;               // wave-uniform base; HW adds lane*16
  gload_lds16(gw0, lx);
  gload_lds16(gw1, lx + 8192);
}

__device__ inline void stage_w64(char* buf, const __hip_bfloat16* __restrict__ w1t,
                                 int n0, int k0, int wid, int l) {
  stage_w(buf,         w1t, n0, k0,      wid, l);   // K32 half A
  stage_w(buf + 16384, w1t, n0, k0 + 32, wid, l);   // K32 half B
}

__device__ __forceinline__ void refill(bf16x8 (&xf)[4], const char* __restrict__ xbase, int u) {
  #pragma unroll
  for (int bi = 0; bi < 4; ++bi)
    xf[bi] = *(const bf16x8*)(xbase + (u * 4 + bi) * 1024);
}

__device__ __forceinline__ void half_mfma(const char* hbuf, f32x4 (&acc)[8][4],
                                          bf16x8 (&xfu)[4], int wbase) {
  bf16x8 w0  = *(const bf16x8*)(hbuf + wbase);
  bf16x8 w1f = *(const bf16x8*)(hbuf + wbase + 1024);
  #pragma unroll
  for (int g = 0; g < 4; ++g) {
    bf16x8 nw0, nw1;
    if (g < 3) {
      nw0 = *(const bf16x8*)(hbuf + wbase + (2 * g + 2) * 1024);
      nw1 = *(const bf16x8*)(hbuf + wbase + (2 * g + 3) * 1024);
    }
    __builtin_amdgcn_s_setprio(1);
    #pragma unroll
    for (int bi = 0; bi < 4; ++bi)
      acc[2 * g][bi] = __builtin_amdgcn_mfma_f32_16x16x32_bf16(w0, xfu[bi], acc[2 * g][bi], 0, 0, 0);
    #pragma unroll
    for (int bi = 0; bi < 4; ++bi)
      acc[2 * g + 1][bi] = __builtin_amdgcn_mfma_f32_16x16x32_bf16(w1f, xfu[bi], acc[2 * g + 1][bi], 0, 0, 0);
    __builtin_amdgcn_s_setprio(0);
    if (g < 3) { w0 = nw0; w1f = nw1; }
  }
}

__global__ __launch_bounds__(512, 2) void gemm_fused(
    const __hip_bfloat16* __restrict__ xsf,   // fragment-linear X
    const __hip_bfloat16* __restrict__ w1t,   // [THD][TFD]
    const float* __restrict__ b1,             // [THD]
    const __hip_bfloat16* __restrict__ w2t,   // [FF][THD] bf16
    float* __restrict__ partial)              // [8][BATCH][FF]
{
  __shared__ __align__(16) char lds[131072];  // 4 x 32KB K64 W buffers
  const int tid = threadIdx.x;
  const int wid = tid >> 6, l = tid & 63;
  const int mq = wid >> 2, bq = wid & 3;      // wave: n_w1-half (2) x batch-quarter (4)
  const int lo = l & 15, hi = l >> 4;
  const int rl = lo >> 1;
  const int cofs = (((((lo & 1) << 2) | hi) ^ rl) << 4);
  const int strip = blockIdx.x & 7;           // strip == XCD -> W slice L2-resident
  const int bt = blockIdx.x >> 3;
  const int b0 = bt * 256;

  const int wbase = ((mq << 6) + rl) * 128 + cofs;              // + mi*1024
  const char* xbase = (const char*)xsf + ((size_t)(bt * 4 + bq) * 16384 + l) * 16;

  f32x4 acc2[2][4];                           // emb^T partial: [f-frag][batch-frag]
  #pragma unroll
  for (int fi = 0; fi < 2; ++fi)
    #pragma unroll
    for (int bi = 0; bi < 4; ++bi) { f32x4 z = {0.f,0.f,0.f,0.f}; acc2[fi][bi] = z; }

  for (int s = 0; s < 4; ++s) {
    const int n0 = strip * 1024 + s * 256;

    f32x4 acc[8][4];
    #pragma unroll
    for (int mi = 0; mi < 8; ++mi)
      #pragma unroll
      for (int bi = 0; bi < 4; ++bi) { f32x4 z = {0.f,0.f,0.f,0.f}; acc[mi][bi] = z; }

    bf16x8 xf0[4], xf1[4];
    // ---- prologue: S(0), S(1), refills u=0,1 (mirror order for mq=1) ----
    stage_w64(lds,         w1t, n0, 0,  wid, l); SCHED;
    stage_w64(lds + 32768, w1t, n0, 64, wid, l); SCHED;
    if (mq == 0) { refill(xf0, xbase, 0); SCHED; refill(xf1, xbase, 1); }
    else         { refill(xf1, xbase, 1); SCHED; refill(xf0, xbase, 0); }
    SCHED;
    VMW(12); SCHED;                // drain S(0); keep {S(1), Rf, Rs}
    __builtin_amdgcn_s_barrier(); SCHED;

    for (int t = 0; t < 30; ++t) {
      stage_w64(lds + ((t + 2) & 3) * 32768, w1t, n0, (t + 2) * 64, wid, l);
      SCHED;
      const char* buf = lds + (t & 3) * 32768;
      if (mq == 0) {
        VMW(8); SCHED;                                     // drain xf0 refill (u=2t)
        half_mfma(buf, acc, xf0, wbase);                   // half A
        refill(xf0, xbase, 2 * t + 2); SCHED;
        VMW(8); SCHED;                                     // drain xf1 refill (u=2t+1)
        half_mfma(buf + 16384, acc, xf1, wbase);           // half B
        refill(xf1, xbase, 2 * t + 3); SCHED;
        VMW(8); SCHED;                                     // drain S(t+2) (publish)
      } else {
        VMW(8); SCHED;                                     // drain xf1 refill (u=2t+1)
        half_mfma(buf + 16384, acc, xf1, wbase);           // half B FIRST (anti-phase)
        refill(xf1, xbase, 2 * t + 3); SCHED;
        VMW(8); SCHED;                                     // drain xf0 refill (u=2t)
        half_mfma(buf, acc, xf0, wbase);                   // half A
        refill(xf0, xbase, 2 * t + 2); SCHED;
        VMW(8); SCHED;
      }
      if (!(t & 1)) { __builtin_amdgcn_s_barrier(); SCHED; }
    }
    // ---- t = 30 (buf 2; no stage) ----
    {
      const char* buf = lds + 2 * 32768;
      if (mq == 0) {
        VMW(4); SCHED; half_mfma(buf, acc, xf0, wbase);
        refill(xf0, xbase, 62); SCHED;
        VMW(4); SCHED; half_mfma(buf + 16384, acc, xf1, wbase);
        refill(xf1, xbase, 63); SCHED;
      } else {
        VMW(4); SCHED; half_mfma(buf + 16384, acc, xf1, wbase);
        refill(xf1, xbase, 63); SCHED;
        VMW(4); SCHED; half_mfma(buf, acc, xf0, wbase);
        refill(xf0, xbase, 62); SCHED;
      }
      __builtin_amdgcn_s_barrier(); SCHED;
    }
    // ---- t = 31 (buf 3) ----
    {
      const char* buf = lds + 3 * 32768;
      if (mq == 0) {
        VMW(4); SCHED; half_mfma(buf, acc, xf0, wbase);
        SCHED; VMW(0); SCHED; half_mfma(buf + 16384, acc, xf1, wbase);
      } else {
        VMW(4); SCHED; half_mfma(buf + 16384, acc, xf1, wbase);
        SCHED; VMW(0); SCHED; half_mfma(buf, acc, xf0, wbase);
      }
    }

    // ---- epilogue: bias+relu+pack in regs, GEMM2 on matrix pipe ----
    #pragma unroll
    for (int mi = 0; mi < 8; ++mi) {
      const int nbase = n0 + (mq << 7) + (mi << 4);
      const float4 b1v = *(const float4*)(b1 + nbase + (hi << 2));
      bf16x4 p[4];
      #pragma unroll
      for (int bi = 0; bi < 4; ++bi) {
        bf16x4 pk;
        #pragma unroll
        for (int j = 0; j < 4; ++j) {
          float v = acc[mi][bi][j] + ((const float*)&b1v)[j];
          v = v > 0.f ? v : 0.f;
          pk[j] = f32_to_bf16_bits(v);
        }
        p[bi] = pk;
      }
      bf16x4 a2[2];
      #pragma unroll
      for (int fi = 0; fi < 2; ++fi)
        a2[fi] = *(const bf16x4*)(w2t + (size_t)(fi * 16 + lo) * THD + nbase + (hi << 2));
      #pragma unroll
      for (int fi = 0; fi < 2; ++fi)
        #pragma unroll
        for (int bi = 0; bi < 4; ++bi)
          acc2[fi][bi] = mfma16x16x16_bf16(a2[fi], p[bi], acc2[fi][bi]);
    }
  }

  // ---- merge the two mq-halves via LDS, then store ----
  float* sm = (float*)lds;                    // [256][32] f32 (32KB = buf0; all reads done)
  if (mq == 1) {
    #pragma unroll
    for (int fi = 0; fi < 2; ++fi)
      #pragma unroll
      for (int bi = 0; bi < 4; ++bi)
        *(f32x4*)(sm + ((bq << 6) + (bi << 4) + lo) * 32 + fi * 16 + (hi << 2)) = acc2[fi][bi];
  }
  __syncthreads();
  if (mq == 0) {
    #pragma unroll
    for (int fi = 0; fi < 2; ++fi)
      #pragma unroll
      for (int bi = 0; bi < 4; ++bi) {
        f32x4 other = *(const f32x4*)(sm + ((bq << 6) + (bi << 4) + lo) * 32 + fi * 16 + (hi << 2));
        f32x4 v = acc2[fi][bi] + other;
        *(f32x4*)(partial + ((size_t)strip * BATCH + b0 + (bq << 6) + (bi << 4) + lo) * FF + fi * 16 + (hi << 2)) = v;
      }
  }
}

// out[b][f] = beff[f] + sum_c partial[c][b][f]
__global__ void reduce_partial(const float* __restrict__ partial, const float* __restrict__ beff,
                               float* __restrict__ out) {
  const int idx = blockIdx.x * 256 + threadIdx.x;
  float s = beff[idx & 31];
  #pragma unroll
  for (int c = 0; c < 8; ++c) s += partial[(size_t)c * BATCH * FF + idx];
  out[idx] = s;
}

// ---------------- launch ----------------

extern "C" void kernel_launch(void* const* d_in, const int* in_sizes, int n_in,
                              void* d_out, int out_size, void* d_ws, size_t ws_size,
                              hipStream_t stream) {
  const float* x      = (const float*)d_in[0];
  const float* W1     = (const float*)d_in[1];
  const float* b1     = (const float*)d_in[2];
  const float* W2     = (const float*)d_in[3];
  const float* b2     = (const float*)d_in[4];
  const float* weight = (const float*)d_in[5];
  const float* bias   = (const float*)d_in[6];
  const int*   sidx   = (const int*)d_in[7];

  char* ws = (char*)d_ws;
  // ws layout (bytes):
  //   xsf     [16384][2048] bf16 (frag-linear) : 0 .. 67108864
  //   w1t     [8192][2048]  bf16 :  67108864 .. 100663296
  //   w2t     [32][8192]    bf16 : 100663296 .. 101187584
  //   beff    [32]          f32  : 101187584 .. 101187712
  //   partial [8][16384][32] f32 : 101188608 .. 117965824
  __hip_bfloat16* xsf  = (__hip_bfloat16*)ws;
  __hip_bfloat16* w1t  = (__hip_bfloat16*)(ws + 67108864);
  __hip_bfloat16* w2t  = (__hip_bfloat16*)(ws + 100663296);
  float*          beff = (float*)(ws + 101187584);
  float*          part = (float*)(ws + 101188608);

  hipLaunchKernelGGL(gather_cast_frag, dim3(1024), dim3(256), 0, stream, x, sidx, xsf);
  hipLaunchKernelGGL(transpose_w1, dim3(32, 128), dim3(256), 0, stream, W1, w1t);
  hipLaunchKernelGGL(make_w2eff,   dim3(1024),    dim3(256), 0, stream, W2, b2, weight, bias, w2t, beff);
  hipLaunchKernelGGL(gemm_fused,   dim3(512),     dim3(512), 0, stream, xsf, w1t, b1, w2t, part);
  hipLaunchKernelGGL(reduce_partial, dim3(2048),  dim3(256), 0, stream, part, beff, (float*)d_out);
}

// Round 12
// 621.268 us; speedup vs baseline: 1.4464x; 1.4464x over previous
//
#include <hip/hip_runtime.h>
#include <hip/hip_bf16.h>

// Problem dims (fixed by reference)
#define BATCH 16384
#define TT    64
#define INF   48
#define FF    32
#define TFD   2048   // T*F   (GEMM1 K)
#define THD   8192   // T*H   (GEMM1 N)

typedef __attribute__((ext_vector_type(8))) short bf16x8;
typedef __attribute__((ext_vector_type(4))) short bf16x4;
typedef __attribute__((ext_vector_type(4))) short short4v;
typedef __attribute__((ext_vector_type(4))) float f32x4;

#define SCHED __builtin_amdgcn_sched_barrier(0)
#define VMW(n) asm volatile("s_waitcnt vmcnt(" #n ")" ::: "memory")
#define LGKM0  asm volatile("s_waitcnt lgkmcnt(0)" ::: "memory")

__device__ inline void gload_lds16(const void* g, void* l) {
  __builtin_amdgcn_global_load_lds((const __attribute__((address_space(1))) void*)g,
                                   (__attribute__((address_space(3))) void*)l, 16, 0, 0);
}

__device__ inline f32x4 mfma16x16x16_bf16(bf16x4 a, bf16x4 b, f32x4 c) {
#if __has_builtin(__builtin_amdgcn_mfma_f32_16x16x16bf16_1k)
  return __builtin_amdgcn_mfma_f32_16x16x16bf16_1k(a, b, c, 0, 0, 0);
#else
  asm("v_mfma_f32_16x16x16_bf16 %0, %1, %2, %0" : "+v"(c) : "v"(a), "v"(b));
  return c;
#endif
}

__device__ inline short f32_to_bf16_bits(float x) {
  __hip_bfloat16 h = __float2bfloat16(x);
  return *reinterpret_cast<short*>(&h);
}

// ---------------- prep kernels ----------------

// xsf: fragment-linear X. Slot (g64, t, bi, lane):
//   element j: bf16( x[g64*64 + bi*16 + (lane&15)][t][sidx[(lane>>4)*8 + j]] )
__global__ void gather_cast_frag(const float* __restrict__ x, const int* __restrict__ sidx,
                                 __hip_bfloat16* __restrict__ xsf) {
  __shared__ int sx[FF];
  if (threadIdx.x < FF) sx[threadIdx.x] = sidx[threadIdx.x];
  __syncthreads();
  const int b64 = blockIdx.x >> 2;          // 0..255
  const int tq  = blockIdx.x & 3;           // t-quarter
  for (int it = 0; it < 16; ++it) {
    const int slot = (tq * 16 + it) * 256 + threadIdx.x;   // ((t*4+bi)*64+l)
    const int t  = slot >> 8;
    const int bi = (slot >> 6) & 3;
    const int l  = slot & 63;
    const int lo = l & 15, hi = l >> 4;
    const int row = b64 * 64 + bi * 16 + lo;
    const float* rp = x + ((size_t)row * TT + t) * INF;
    bf16x8 v;
    #pragma unroll
    for (int j = 0; j < 8; ++j) v[j] = f32_to_bf16_bits(rp[sx[hi * 8 + j]]);
    *(bf16x8*)(xsf + ((size_t)b64 * 16384 + slot) * 8) = v;
  }
}

// W1t[n][k] = bf16(W1[k][n]);  W1: [TFD][THD] row-major. ushort4 stores.
__global__ void transpose_w1(const float* __restrict__ W1, __hip_bfloat16* __restrict__ W1t) {
  __shared__ float tile[64][65];
  const int k0 = blockIdx.x * 64;
  const int n0 = blockIdx.y * 64;
  const int tx = threadIdx.x & 63, ty = threadIdx.x >> 6;
  for (int r = ty; r < 64; r += 4)
    tile[r][tx] = W1[(size_t)(k0 + r) * THD + n0 + tx];
  __syncthreads();
  const int rn = threadIdx.x >> 4;          // 0..15
  const int kq = (threadIdx.x & 15) * 4;    // k-quad
  for (int rr = rn; rr < 64; rr += 16) {
    short4v v;
    #pragma unroll
    for (int i = 0; i < 4; ++i) v[i] = f32_to_bf16_bits(tile[kq + i][rr]);
    *(short4v*)(W1t + (size_t)(n0 + rr) * TFD + k0 + kq) = v;
  }
}

// w2t[f][n] = bf16( sum_t W2[n][t*32+f]*weight[t][f] );  beff[f] = bias[f] + sum_t b2[t*32+f]*weight[t][f]
__global__ void make_w2eff(const float* __restrict__ W2, const float* __restrict__ b2,
                           const float* __restrict__ weight, const float* __restrict__ bias,
                           __hip_bfloat16* __restrict__ w2t, float* __restrict__ beff) {
  const int n = blockIdx.x * 8 + (threadIdx.x >> 5);
  const int f = threadIdx.x & 31;
  const float* wr = W2 + (size_t)n * TFD;
  float s = 0.f;
  #pragma unroll 8
  for (int t = 0; t < TT; ++t) s += wr[t * FF + f] * weight[t * FF + f];
  w2t[(size_t)f * THD + n] = __float2bfloat16(s);
  if (blockIdx.x == 0 && threadIdx.x < FF) {
    float sb = bias[f];
    for (int t = 0; t < TT; ++t) sb += b2[t * FF + f] * weight[t * FF + f];
    beff[f] = sb;
  }
}

// ---------------- main fused GEMM ----------------
// r12 = faithful m201 8-phase-template port at r9 geometry (256b x 256n,
// 8 waves = 2 mq x 4 bq, 1 block/CU). BOTH operands staged via gload_lds
// into LDS (r11's per-wave global X refills + mq-mirrored loop spilled:
// WRITE_SIZE 41->751MB). Tile = K32: W 16KB (paired-row + XOR swizzle,
// conflict-free) + X 16KB (fragment-linear from xsf; stride-1 reads,
// conflict-free). 4 buffers x 32KB = 128KB, staged 2 tiles ahead.
// Per tile TWO phases (template density: 4-8 ds_read + 2 G-loads + 16 MFMA
// between paired barriers):
//  ph0: {4 wf(mlow) + 4 xf ds_read || stage_w(t+2)} bar lgkm0 prio1 16MFMA prio0 bar
//  ph1: {4 wf(mhigh) ds_read       || stage_x(t+2)} bar lgkm0 prio1 16MFMA prio0
//       vmcnt(4) bar
// vmcnt ledger (4 loads/tile: 2 W + 2 X): end of tile t outstanding =
// {stage(t+1) 4, stage(t+2) 4} -> vmcnt(4) drains stage(t+1) before tile
// t+1's reads. Tails: t=62 -> vmcnt(0) (drains stage(63)); t=63 none.
// Prologue: stage(0),stage(1) = 8 -> vmcnt(4) -> barrier.

__device__ inline void stage_w(char* buf, const __hip_bfloat16* __restrict__ w1t,
                               int n0, int k0, int wid, int l) {
  const int sub = l >> 3;
  const int c   = (l & 7) ^ sub;             // inverse chunk swizzle
  const int h   = c >> 2, kc = c & 3;
  const int r0  = wid * 8 + sub;             // lds row (128B rows, 2 logical rows each)
  const __hip_bfloat16* gw0 = w1t + (size_t)(n0 + 2 * r0 + h) * TFD + k0 + kc * 8;
  const __hip_bfloat16* gw1 = w1t + (size_t)(n0 + 128 + 2 * r0 + h) * TFD + k0 + kc * 8;
  char* lx = buf + wid * 1024;               // wave-uniform base; HW adds lane*16
  gload_lds16(gw0, lx);
  gload_lds16(gw1, lx + 8192);
}

// X tile 16KB: [g64 g: 4KB][bi: 1KB][lane: 16B], copied linearly from xsf.
// Wave wid stages 2KB: g = wid>>1, bi0 = (wid&1)*2, two 1KB chunks.
__device__ inline void stage_x(char* bufX, const char* __restrict__ xg, int t, int wid, int l) {
  const int g = wid >> 1, bi0 = (wid & 1) * 2;
  const char* src = xg + (size_t)g * 262144 + ((t * 4 + bi0) * 1024) + l * 16;
  char* dst = bufX + g * 4096 + bi0 * 1024;  // wave-uniform; HW adds lane*16
  gload_lds16(src, dst);
  gload_lds16(src + 1024, dst + 1024);
}

__global__ __launch_bounds__(512, 2) void gemm_fused(
    const __hip_bfloat16* __restrict__ xsf,   // fragment-linear X
    const __hip_bfloat16* __restrict__ w1t,   // [THD][TFD]
    const float* __restrict__ b1,             // [THD]
    const __hip_bfloat16* __restrict__ w2t,   // [FF][THD] bf16
    float* __restrict__ partial)              // [8][BATCH][FF]
{
  __shared__ __align__(16) char lds[131072];  // 4 x (W 16KB + X 16KB)
  const int tid = threadIdx.x;
  const int wid = tid >> 6, l = tid & 63;
  const int mq = wid >> 2, bq = wid & 3;      // wave: n_w1-half (2) x batch-quarter (4)
  const int lo = l & 15, hi = l >> 4;
  const int rl = lo >> 1;
  const int cofs = (((((lo & 1) << 2) | hi) ^ rl) << 4);
  const int strip = blockIdx.x & 7;           // strip == XCD -> W slice L2-resident
  const int bt = blockIdx.x >> 3;
  const int b0 = bt * 256;

  const int wbase = ((mq << 6) + rl) * 128 + cofs;   // + mi*1024 per frag
  const int xoff  = (bq << 12) + l * 16;             // + bi*1024 per frag (at buf+16384)
  const char* xg  = (const char*)xsf + (size_t)(bt * 4) * 262144;  // block's 4 g64 groups

  f32x4 acc2[2][4];                           // emb^T partial: [f-frag][batch-frag]
  #pragma unroll
  for (int fi = 0; fi < 2; ++fi)
    #pragma unroll
    for (int bi = 0; bi < 4; ++bi) { f32x4 z = {0.f,0.f,0.f,0.f}; acc2[fi][bi] = z; }

  for (int s = 0; s < 4; ++s) {
    const int n0 = strip * 1024 + s * 256;

    f32x4 acc[8][4];
    #pragma unroll
    for (int mi = 0; mi < 8; ++mi)
      #pragma unroll
      for (int bi = 0; bi < 4; ++bi) { f32x4 z = {0.f,0.f,0.f,0.f}; acc[mi][bi] = z; }

    // ---- prologue: stage tiles 0,1; drain tile0; barrier ----
    stage_w(lds, w1t, n0, 0, wid, l);
    stage_x(lds + 16384, xg, 0, wid, l);
    SCHED;
    stage_w(lds + 32768, w1t, n0, 32, wid, l);
    stage_x(lds + 32768 + 16384, xg, 1, wid, l);
    SCHED;
    VMW(4); SCHED;
    __builtin_amdgcn_s_barrier(); SCHED;

    for (int t = 0; t < 64; ++t) {
      char* buf  = lds + (size_t)(t & 3) * 32768;
      char* nbuf = lds + (size_t)((t + 2) & 3) * 32768;

      // ======== phase 0: mlow ========
      bf16x8 wf0 = *(const bf16x8*)(buf + wbase);
      bf16x8 wf1 = *(const bf16x8*)(buf + wbase + 1024);
      bf16x8 wf2 = *(const bf16x8*)(buf + wbase + 2048);
      bf16x8 wf3 = *(const bf16x8*)(buf + wbase + 3072);
      bf16x8 xf0 = *(const bf16x8*)(buf + 16384 + xoff);
      bf16x8 xf1 = *(const bf16x8*)(buf + 16384 + xoff + 1024);
      bf16x8 xf2 = *(const bf16x8*)(buf + 16384 + xoff + 2048);
      bf16x8 xf3 = *(const bf16x8*)(buf + 16384 + xoff + 3072);
      if (t < 62) stage_w(nbuf, w1t, n0, (t + 2) * 32, wid, l);
      SCHED;
      __builtin_amdgcn_s_barrier();
      LGKM0; SCHED;
      __builtin_amdgcn_s_setprio(1);
      acc[0][0] = __builtin_amdgcn_mfma_f32_16x16x32_bf16(wf0, xf0, acc[0][0], 0, 0, 0);
      acc[0][1] = __builtin_amdgcn_mfma_f32_16x16x32_bf16(wf0, xf1, acc[0][1], 0, 0, 0);
      acc[0][2] = __builtin_amdgcn_mfma_f32_16x16x32_bf16(wf0, xf2, acc[0][2], 0, 0, 0);
      acc[0][3] = __builtin_amdgcn_mfma_f32_16x16x32_bf16(wf0, xf3, acc[0][3], 0, 0, 0);
      acc[1][0] = __builtin_amdgcn_mfma_f32_16x16x32_bf16(wf1, xf0, acc[1][0], 0, 0, 0);
      acc[1][1] = __builtin_amdgcn_mfma_f32_16x16x32_bf16(wf1, xf1, acc[1][1], 0, 0, 0);
      acc[1][2] = __builtin_amdgcn_mfma_f32_16x16x32_bf16(wf1, xf2, acc[1][2], 0, 0, 0);
      acc[1][3] = __builtin_amdgcn_mfma_f32_16x16x32_bf16(wf1, xf3, acc[1][3], 0, 0, 0);
      acc[2][0] = __builtin_amdgcn_mfma_f32_16x16x32_bf16(wf2, xf0, acc[2][0], 0, 0, 0);
      acc[2][1] = __builtin_amdgcn_mfma_f32_16x16x32_bf16(wf2, xf1, acc[2][1], 0, 0, 0);
      acc[2][2] = __builtin_amdgcn_mfma_f32_16x16x32_bf16(wf2, xf2, acc[2][2], 0, 0, 0);
      acc[2][3] = __builtin_amdgcn_mfma_f32_16x16x32_bf16(wf2, xf3, acc[2][3], 0, 0, 0);
      acc[3][0] = __builtin_amdgcn_mfma_f32_16x16x32_bf16(wf3, xf0, acc[3][0], 0, 0, 0);
      acc[3][1] = __builtin_amdgcn_mfma_f32_16x16x32_bf16(wf3, xf1, acc[3][1], 0, 0, 0);
      acc[3][2] = __builtin_amdgcn_mfma_f32_16x16x32_bf16(wf3, xf2, acc[3][2], 0, 0, 0);
      acc[3][3] = __builtin_amdgcn_mfma_f32_16x16x32_bf16(wf3, xf3, acc[3][3], 0, 0, 0);
      __builtin_amdgcn_s_setprio(0);
      SCHED;
      __builtin_amdgcn_s_barrier();

      // ======== phase 1: mhigh ========
      bf16x8 wf4 = *(const bf16x8*)(buf + wbase + 4096);
      bf16x8 wf5 = *(const bf16x8*)(buf + wbase + 5120);
      bf16x8 wf6 = *(const bf16x8*)(buf + wbase + 6144);
      bf16x8 wf7 = *(const bf16x8*)(buf + wbase + 7168);
      if (t < 62) stage_x(nbuf + 16384, xg, t + 2, wid, l);
      SCHED;
      __builtin_amdgcn_s_barrier();
      LGKM0; SCHED;
      __builtin_amdgcn_s_setprio(1);
      acc[4][0] = __builtin_amdgcn_mfma_f32_16x16x32_bf16(wf4, xf0, acc[4][0], 0, 0, 0);
      acc[4][1] = __builtin_amdgcn_mfma_f32_16x16x32_bf16(wf4, xf1, acc[4][1], 0, 0, 0);
      acc[4][2] = __builtin_amdgcn_mfma_f32_16x16x32_bf16(wf4, xf2, acc[4][2], 0, 0, 0);
      acc[4][3] = __builtin_amdgcn_mfma_f32_16x16x32_bf16(wf4, xf3, acc[4][3], 0, 0, 0);
      acc[5][0] = __builtin_amdgcn_mfma_f32_16x16x32_bf16(wf5, xf0, acc[5][0], 0, 0, 0);
      acc[5][1] = __builtin_amdgcn_mfma_f32_16x16x32_bf16(wf5, xf1, acc[5][1], 0, 0, 0);
      acc[5][2] = __builtin_amdgcn_mfma_f32_16x16x32_bf16(wf5, xf2, acc[5][2], 0, 0, 0);
      acc[5][3] = __builtin_amdgcn_mfma_f32_16x16x32_bf16(wf5, xf3, acc[5][3], 0, 0, 0);
      acc[6][0] = __builtin_amdgcn_mfma_f32_16x16x32_bf16(wf6, xf0, acc[6][0], 0, 0, 0);
      acc[6][1] = __builtin_amdgcn_mfma_f32_16x16x32_bf16(wf6, xf1, acc[6][1], 0, 0, 0);
      acc[6][2] = __builtin_amdgcn_mfma_f32_16x16x32_bf16(wf6, xf2, acc[6][2], 0, 0, 0);
      acc[6][3] = __builtin_amdgcn_mfma_f32_16x16x32_bf16(wf6, xf3, acc[6][3], 0, 0, 0);
      acc[7][0] = __builtin_amdgcn_mfma_f32_16x16x32_bf16(wf7, xf0, acc[7][0], 0, 0, 0);
      acc[7][1] = __builtin_amdgcn_mfma_f32_16x16x32_bf16(wf7, xf1, acc[7][1], 0, 0, 0);
      acc[7][2] = __builtin_amdgcn_mfma_f32_16x16x32_bf16(wf7, xf2, acc[7][2], 0, 0, 0);
      acc[7][3] = __builtin_amdgcn_mfma_f32_16x16x32_bf16(wf7, xf3, acc[7][3], 0, 0, 0);
      __builtin_amdgcn_s_setprio(0);
      SCHED;
      if (t < 62)       { VMW(4); }
      else if (t == 62) { VMW(0); }
      SCHED;
      __builtin_amdgcn_s_barrier();
      SCHED;
    }

    // ---- epilogue: bias+relu+pack in regs, GEMM2 on matrix pipe ----
    #pragma unroll
    for (int mi = 0; mi < 8; ++mi) {
      const int nbase = n0 + (mq << 7) + (mi << 4);
      const float4 b1v = *(const float4*)(b1 + nbase + (hi << 2));
      bf16x4 p[4];
      #pragma unroll
      for (int bi = 0; bi < 4; ++bi) {
        bf16x4 pk;
        #pragma unroll
        for (int j = 0; j < 4; ++j) {
          float v = acc[mi][bi][j] + ((const float*)&b1v)[j];
          v = v > 0.f ? v : 0.f;
          pk[j] = f32_to_bf16_bits(v);
        }
        p[bi] = pk;
      }
      bf16x4 a2[2];
      #pragma unroll
      for (int fi = 0; fi < 2; ++fi)
        a2[fi] = *(const bf16x4*)(w2t + (size_t)(fi * 16 + lo) * THD + nbase + (hi << 2));
      #pragma unroll
      for (int fi = 0; fi < 2; ++fi)
        #pragma unroll
        for (int bi = 0; bi < 4; ++bi)
          acc2[fi][bi] = mfma16x16x16_bf16(a2[fi], p[bi], acc2[fi][bi]);
    }
  }

  // ---- merge the two mq-halves via LDS, then store ----
  float* sm = (float*)lds;                    // [256][32] f32 (32KB; buffers dead)
  if (mq == 1) {
    #pragma unroll
    for (int fi = 0; fi < 2; ++fi)
      #pragma unroll
      for (int bi = 0; bi < 4; ++bi)
        *(f32x4*)(sm + ((bq << 6) + (bi << 4) + lo) * 32 + fi * 16 + (hi << 2)) = acc2[fi][bi];
  }
  __syncthreads();
  if (mq == 0) {
    #pragma unroll
    for (int fi = 0; fi < 2; ++fi)
      #pragma unroll
      for (int bi = 0; bi < 4; ++bi) {
        f32x4 other = *(const f32x4*)(sm + ((bq << 6) + (bi << 4) + lo) * 32 + fi * 16 + (hi << 2));
        f32x4 v = acc2[fi][bi] + other;
        *(f32x4*)(partial + ((size_t)strip * BATCH + b0 + (bq << 6) + (bi << 4) + lo) * FF + fi * 16 + (hi << 2)) = v;
      }
  }
}

// out[b][f] = beff[f] + sum_c partial[c][b][f]
__global__ void reduce_partial(const float* __restrict__ partial, const float* __restrict__ beff,
                               float* __restrict__ out) {
  const int idx = blockIdx.x * 256 + threadIdx.x;
  float s = beff[idx & 31];
  #pragma unroll
  for (int c = 0; c < 8; ++c) s += partial[(size_t)c * BATCH * FF + idx];
  out[idx] = s;
}

// ---------------- launch ----------------

extern "C" void kernel_launch(void* const* d_in, const int* in_sizes, int n_in,
                              void* d_out, int out_size, void* d_ws, size_t ws_size,
                              hipStream_t stream) {
  const float* x      = (const float*)d_in[0];
  const float* W1     = (const float*)d_in[1];
  const float* b1     = (const float*)d_in[2];
  const float* W2     = (const float*)d_in[3];
  const float* b2     = (const float*)d_in[4];
  const float* weight = (const float*)d_in[5];
  const float* bias   = (const float*)d_in[6];
  const int*   sidx   = (const int*)d_in[7];

  char* ws = (char*)d_ws;
  // ws layout (bytes):
  //   xsf     [16384][2048] bf16 (frag-linear) : 0 .. 67108864
  //   w1t     [8192][2048]  bf16 :  67108864 .. 100663296
  //   w2t     [32][8192]    bf16 : 100663296 .. 101187584
  //   beff    [32]          f32  : 101187584 .. 101187712
  //   partial [8][16384][32] f32 : 101188608 .. 117965824
  __hip_bfloat16* xsf  = (__hip_bfloat16*)ws;
  __hip_bfloat16* w1t  = (__hip_bfloat16*)(ws + 67108864);
  __hip_bfloat16* w2t  = (__hip_bfloat16*)(ws + 100663296);
  float*          beff = (float*)(ws + 101187584);
  float*          part = (float*)(ws + 101188608);

  hipLaunchKernelGGL(gather_cast_frag, dim3(1024), dim3(256), 0, stream, x, sidx, xsf);
  hipLaunchKernelGGL(transpose_w1, dim3(32, 128), dim3(256), 0, stream, W1, w1t);
  hipLaunchKernelGGL(make_w2eff,   dim3(1024),    dim3(256), 0, stream, W2, b2, weight, bias, w2t, beff);
  hipLaunchKernelGGL(gemm_fused,   dim3(512),     dim3(512), 0, stream, xsf, w1t, b1, w2t, part);
  hipLaunchKernelGGL(reduce_partial, dim3(2048),  dim3(256), 0, stream, part, beff, (float*)d_out);
}